// Round 9
// baseline (910.070 us; speedup 1.0000x reference)
//
#include <hip/hip_runtime.h>
#include <math.h>

#define N_NODES 50000
#define N_EDGES 500000

// ws layout (float element offsets)
#define OFF_QN  0
#define OFF_KN  6400000
#define OFF_VN  12800000
#define OFF_DEN 19200000
#define OFF_AGG 19600000
#define OFF_UPD OFF_VN   // vn dead after edge kernel
#define OFF_FF1 OFF_QN   // qn+kn dead after edge kernel (12.8M floats for [N,256])

__global__ void k_zero(float* __restrict__ p, int n4) {
    int i = blockIdx.x * blockDim.x + threadIdx.x;
    int stride = gridDim.x * blockDim.x;
    float4 z = {0.f, 0.f, 0.f, 0.f};
    for (int j = i; j < n4; j += stride) ((float4*)p)[j] = z;
}

#define FMA16()                                                                 \
    {                                                                           \
        float4 b = *(float4*)&Bs[kk][tx << 2];                                  \
        float a0 = As[ty4 + 0][kk], a1 = As[ty4 + 1][kk];                       \
        float a2 = As[ty4 + 2][kk], a3 = As[ty4 + 3][kk];                       \
        acc[0][0] = fmaf(a0, b.x, acc[0][0]); acc[0][1] = fmaf(a0, b.y, acc[0][1]); \
        acc[0][2] = fmaf(a0, b.z, acc[0][2]); acc[0][3] = fmaf(a0, b.w, acc[0][3]); \
        acc[1][0] = fmaf(a1, b.x, acc[1][0]); acc[1][1] = fmaf(a1, b.y, acc[1][1]); \
        acc[1][2] = fmaf(a1, b.z, acc[1][2]); acc[1][3] = fmaf(a1, b.w, acc[1][3]); \
        acc[2][0] = fmaf(a2, b.x, acc[2][0]); acc[2][1] = fmaf(a2, b.y, acc[2][1]); \
        acc[2][2] = fmaf(a2, b.z, acc[2][2]); acc[2][3] = fmaf(a2, b.w, acc[2][3]); \
        acc[3][0] = fmaf(a3, b.x, acc[3][0]); acc[3][1] = fmaf(a3, b.y, acc[3][1]); \
        acc[3][2] = fmaf(a3, b.z, acc[3][2]); acc[3][3] = fmaf(a3, b.w, acc[3][3]); \
    }

// ---------------- Kernel 2: per-node q / k_node / v_node  ----------------
// [N,160] @ [160,128] for each of Wq, Wk[0:160], Wv[0:160]
__global__ __launch_bounds__(256) void k_node_qkv(
    const float* __restrict__ ns, const float* __restrict__ nt,
    const float* __restrict__ Wq, const float* __restrict__ bq,
    const float* __restrict__ Wk, const float* __restrict__ bk,
    const float* __restrict__ Wv, const float* __restrict__ bv,
    float* __restrict__ ws)
{
    const int which = blockIdx.y;
    const float* W    = which == 0 ? Wq : (which == 1 ? Wk : Wv);
    const float* bias = which == 0 ? bq : (which == 1 ? bk : bv);
    float* out = ws + (which == 0 ? OFF_QN : (which == 1 ? OFF_KN : OFF_VN));

    __shared__ float As[32][33];
    __shared__ float Bs[32][128];
    const int tid = threadIdx.x;
    const int tx = tid & 31, ty = tid >> 5, ty4 = ty << 2;
    const int row0 = blockIdx.x * 32;
    float acc[4][4] = {};

    for (int k0 = 0; k0 < 160; k0 += 32) {
        #pragma unroll
        for (int l = 0; l < 4; l++) {
            int idx = tid + l * 256;
            int r = idx >> 5, c = idx & 31;
            int gr = row0 + r, gc = k0 + c;
            float v = 0.f;
            if (gr < N_NODES) v = (gc < 128) ? ns[gr * 128 + gc] : nt[gr * 32 + gc - 128];
            As[r][c] = v;
        }
        #pragma unroll
        for (int l = 0; l < 4; l++) {
            int idx = tid + l * 256;
            int r = idx >> 5, c = (idx & 31) << 2;
            *(float4*)&Bs[r][c] = *(const float4*)&W[(k0 + r) * 128 + c];
        }
        __syncthreads();
        #pragma unroll
        for (int kk = 0; kk < 32; kk++) FMA16();
        __syncthreads();
    }
    float4 bb = *(const float4*)&bias[tx << 2];
    #pragma unroll
    for (int r = 0; r < 4; r++) {
        int gr = row0 + ty4 + r;
        if (gr < N_NODES) {
            float4 o = {acc[r][0] + bb.x, acc[r][1] + bb.y, acc[r][2] + bb.z, acc[r][3] + bb.w};
            *(float4*)&out[gr * 128 + (tx << 2)] = o;
        }
    }
}

// ---------------- Kernel 3: fused edge attention ----------------
// 1 wave handles 1 edge per iteration; lane owns dims 2*lane, 2*lane+1.
// k_e = kn[src] + ee @ WkE, v_e likewise; logit per head; exp; atomic agg.
__global__ __launch_bounds__(256) void k_edge(
    const int* __restrict__ ei, const float* __restrict__ ee,
    const float* __restrict__ WkE, const float* __restrict__ WvE,
    float* __restrict__ ws)
{
    const float* qn = ws + OFF_QN;
    const float* kn = ws + OFF_KN;
    const float* vn = ws + OFF_VN;
    float* den = ws + OFF_DEN;
    float* agg = ws + OFF_AGG;

    const int lane = threadIdx.x & 63;
    const int gwave = (blockIdx.x * blockDim.x + threadIdx.x) >> 6;
    const int nwaves = (gridDim.x * blockDim.x) >> 6;
    const int h = lane >> 3;  // head 0..7 (lane group of 8 owns 16 dims)

    // cache edge-part weights in registers: 2 columns per lane, all 32 rows
    float wk[32][2], wv[32][2];
    #pragma unroll
    for (int j = 0; j < 32; j++) {
        float2 a = *(const float2*)&WkE[j * 128 + 2 * lane];
        wk[j][0] = a.x; wk[j][1] = a.y;
        float2 b = *(const float2*)&WvE[j * 128 + 2 * lane];
        wv[j][0] = b.x; wv[j][1] = b.y;
    }

    for (int e = gwave; e < N_EDGES; e += nwaves) {
        int eu = __builtin_amdgcn_readfirstlane(e);
        int src = ei[eu];
        int tgt = ei[N_EDGES + eu];
        float2 kv = *(const float2*)&kn[src * 128 + 2 * lane];
        float2 vv = *(const float2*)&vn[src * 128 + 2 * lane];
        float k1 = kv.x, k2 = kv.y, v1 = vv.x, v2 = vv.y;
        #pragma unroll
        for (int j = 0; j < 32; j++) {
            float c = ee[eu * 32 + j];  // uniform address -> scalar load
            k1 = fmaf(c, wk[j][0], k1);
            k2 = fmaf(c, wk[j][1], k2);
            v1 = fmaf(c, wv[j][0], v1);
            v2 = fmaf(c, wv[j][1], v2);
        }
        float2 qv = *(const float2*)&qn[tgt * 128 + 2 * lane];
        float p = qv.x * k1 + qv.y * k2;
        p += __shfl_xor(p, 1);
        p += __shfl_xor(p, 2);
        p += __shfl_xor(p, 4);
        float ex = expf(p * 0.25f);  // scale = 1/sqrt(16); max-subtraction not needed (|logit| << 1)
        if ((lane & 7) == 0) atomicAdd(&den[tgt * 8 + h], ex);
        atomicAdd(&agg[tgt * 128 + 2 * lane], ex * v1);
        atomicAdd(&agg[tgt * 128 + 2 * lane + 1], ex * v2);
    }
}

// ---------------- Kernel 4: (agg/den) @ Wo + bo + ns -> LN1 -> upd ----------------
__global__ __launch_bounds__(256) void k_out_ln1(
    const float* __restrict__ ns,
    const float* __restrict__ Wo, const float* __restrict__ bo,
    const float* __restrict__ g1, const float* __restrict__ be1,
    float* __restrict__ ws)
{
    const float* agg = ws + OFF_AGG;
    const float* den = ws + OFF_DEN;
    float* upd = ws + OFF_UPD;
    __shared__ float As[32][33];
    __shared__ float Bs[32][128];
    const int tid = threadIdx.x;
    const int tx = tid & 31, ty = tid >> 5, ty4 = ty << 2;
    const int row0 = blockIdx.x * 32;
    float acc[4][4] = {};

    for (int k0 = 0; k0 < 128; k0 += 32) {
        #pragma unroll
        for (int l = 0; l < 4; l++) {
            int idx = tid + l * 256;
            int r = idx >> 5, c = idx & 31;
            int gr = row0 + r, gc = k0 + c;
            float v = 0.f;
            if (gr < N_NODES) {
                float d = den[gr * 8 + (gc >> 4)];
                v = agg[gr * 128 + gc] / fmaxf(d, 1e-9f);
            }
            As[r][c] = v;
        }
        #pragma unroll
        for (int l = 0; l < 4; l++) {
            int idx = tid + l * 256;
            int r = idx >> 5, c = (idx & 31) << 2;
            *(float4*)&Bs[r][c] = *(const float4*)&Wo[(k0 + r) * 128 + c];
        }
        __syncthreads();
        #pragma unroll
        for (int kk = 0; kk < 32; kk++) FMA16();
        __syncthreads();
    }
    float4 bo4 = *(const float4*)&bo[tx << 2];
    float4 g4  = *(const float4*)&g1[tx << 2];
    float4 b4  = *(const float4*)&be1[tx << 2];
    #pragma unroll
    for (int r = 0; r < 4; r++) {
        int gr = row0 + ty4 + r;
        bool valid = gr < N_NODES;
        float4 t = {0.f, 0.f, 0.f, 0.f};
        if (valid) {
            float4 nsv = *(const float4*)&ns[gr * 128 + (tx << 2)];
            t.x = acc[r][0] + bo4.x + nsv.x;
            t.y = acc[r][1] + bo4.y + nsv.y;
            t.z = acc[r][2] + bo4.z + nsv.z;
            t.w = acc[r][3] + bo4.w + nsv.w;
        }
        float s = t.x + t.y + t.z + t.w;
        s += __shfl_xor(s, 1); s += __shfl_xor(s, 2); s += __shfl_xor(s, 4);
        s += __shfl_xor(s, 8); s += __shfl_xor(s, 16);
        float mu = s * 0.0078125f;
        float dx = t.x - mu, dy = t.y - mu, dz = t.z - mu, dw = t.w - mu;
        float sq = dx * dx + dy * dy + dz * dz + dw * dw;
        sq += __shfl_xor(sq, 1); sq += __shfl_xor(sq, 2); sq += __shfl_xor(sq, 4);
        sq += __shfl_xor(sq, 8); sq += __shfl_xor(sq, 16);
        float rs = rsqrtf(sq * 0.0078125f + 1e-5f);
        if (valid) {
            float4 o;
            o.x = dx * rs * g4.x + b4.x;
            o.y = dy * rs * g4.y + b4.y;
            o.z = dz * rs * g4.z + b4.z;
            o.w = dw * rs * g4.w + b4.w;
            *(float4*)&upd[gr * 128 + (tx << 2)] = o;
        }
    }
}

// ---------------- Kernel 5: upd @ W1 + bf1 -> gelu -> ff1 ----------------
__global__ __launch_bounds__(256) void k_ffn1(
    const float* __restrict__ W1, const float* __restrict__ bf1,
    float* __restrict__ ws)
{
    const float* upd = ws + OFF_UPD;
    float* ff1 = ws + OFF_FF1;
    __shared__ float As[32][33];
    __shared__ float Bs[32][128];
    const int tid = threadIdx.x;
    const int tx = tid & 31, ty = tid >> 5, ty4 = ty << 2;
    const int row0 = blockIdx.x * 32;
    const int colbase = blockIdx.y * 128;
    float acc[4][4] = {};

    for (int k0 = 0; k0 < 128; k0 += 32) {
        #pragma unroll
        for (int l = 0; l < 4; l++) {
            int idx = tid + l * 256;
            int r = idx >> 5, c = idx & 31;
            int gr = row0 + r, gc = k0 + c;
            As[r][c] = (gr < N_NODES) ? upd[gr * 128 + gc] : 0.f;
        }
        #pragma unroll
        for (int l = 0; l < 4; l++) {
            int idx = tid + l * 256;
            int r = idx >> 5, c = (idx & 31) << 2;
            *(float4*)&Bs[r][c] = *(const float4*)&W1[(k0 + r) * 256 + colbase + c];
        }
        __syncthreads();
        #pragma unroll
        for (int kk = 0; kk < 32; kk++) FMA16();
        __syncthreads();
    }
    float4 bb = *(const float4*)&bf1[colbase + (tx << 2)];
    #pragma unroll
    for (int r = 0; r < 4; r++) {
        int gr = row0 + ty4 + r;
        if (gr < N_NODES) {
            float x0 = acc[r][0] + bb.x, x1 = acc[r][1] + bb.y;
            float x2 = acc[r][2] + bb.z, x3 = acc[r][3] + bb.w;
            float4 o;
            o.x = 0.5f * x0 * (1.f + erff(x0 * 0.70710678118654752f));
            o.y = 0.5f * x1 * (1.f + erff(x1 * 0.70710678118654752f));
            o.z = 0.5f * x2 * (1.f + erff(x2 * 0.70710678118654752f));
            o.w = 0.5f * x3 * (1.f + erff(x3 * 0.70710678118654752f));
            *(float4*)&ff1[gr * 256 + colbase + (tx << 2)] = o;
        }
    }
}

// ---------------- Kernel 6: ff1 @ W2 + bf2 + upd -> LN2 -> out ----------------
__global__ __launch_bounds__(256) void k_ffn2(
    const float* __restrict__ W2, const float* __restrict__ bf2,
    const float* __restrict__ g2, const float* __restrict__ be2,
    float* __restrict__ ws, float* __restrict__ out)
{
    const float* ff1 = ws + OFF_FF1;
    const float* upd = ws + OFF_UPD;
    __shared__ float As[32][33];
    __shared__ float Bs[32][128];
    const int tid = threadIdx.x;
    const int tx = tid & 31, ty = tid >> 5, ty4 = ty << 2;
    const int row0 = blockIdx.x * 32;
    float acc[4][4] = {};

    for (int k0 = 0; k0 < 256; k0 += 32) {
        #pragma unroll
        for (int l = 0; l < 4; l++) {
            int idx = tid + l * 256;
            int r = idx >> 5, c = idx & 31;
            int gr = row0 + r, gc = k0 + c;
            As[r][c] = (gr < N_NODES) ? ff1[gr * 256 + gc] : 0.f;
        }
        #pragma unroll
        for (int l = 0; l < 4; l++) {
            int idx = tid + l * 256;
            int r = idx >> 5, c = (idx & 31) << 2;
            *(float4*)&Bs[r][c] = *(const float4*)&W2[(k0 + r) * 128 + c];
        }
        __syncthreads();
        #pragma unroll
        for (int kk = 0; kk < 32; kk++) FMA16();
        __syncthreads();
    }
    float4 bb = *(const float4*)&bf2[tx << 2];
    float4 g4 = *(const float4*)&g2[tx << 2];
    float4 b4 = *(const float4*)&be2[tx << 2];
    #pragma unroll
    for (int r = 0; r < 4; r++) {
        int gr = row0 + ty4 + r;
        bool valid = gr < N_NODES;
        float4 t = {0.f, 0.f, 0.f, 0.f};
        if (valid) {
            float4 uv = *(const float4*)&upd[gr * 128 + (tx << 2)];
            t.x = acc[r][0] + bb.x + uv.x;
            t.y = acc[r][1] + bb.y + uv.y;
            t.z = acc[r][2] + bb.z + uv.z;
            t.w = acc[r][3] + bb.w + uv.w;
        }
        float s = t.x + t.y + t.z + t.w;
        s += __shfl_xor(s, 1); s += __shfl_xor(s, 2); s += __shfl_xor(s, 4);
        s += __shfl_xor(s, 8); s += __shfl_xor(s, 16);
        float mu = s * 0.0078125f;
        float dx = t.x - mu, dy = t.y - mu, dz = t.z - mu, dw = t.w - mu;
        float sq = dx * dx + dy * dy + dz * dz + dw * dw;
        sq += __shfl_xor(sq, 1); sq += __shfl_xor(sq, 2); sq += __shfl_xor(sq, 4);
        sq += __shfl_xor(sq, 8); sq += __shfl_xor(sq, 16);
        float rs = rsqrtf(sq * 0.0078125f + 1e-5f);
        if (valid) {
            float4 o;
            o.x = dx * rs * g4.x + b4.x;
            o.y = dy * rs * g4.y + b4.y;
            o.z = dz * rs * g4.z + b4.z;
            o.w = dw * rs * g4.w + b4.w;
            *(float4*)&out[gr * 128 + (tx << 2)] = o;
        }
    }
}

extern "C" void kernel_launch(void* const* d_in, const int* in_sizes, int n_in,
                              void* d_out, int out_size, void* d_ws, size_t ws_size,
                              hipStream_t stream)
{
    const float* ns  = (const float*)d_in[0];
    const float* nt  = (const float*)d_in[1];
    const int*   ei  = (const int*)d_in[2];
    const float* ee  = (const float*)d_in[3];
    const float* Wq  = (const float*)d_in[4];
    const float* bq  = (const float*)d_in[5];
    const float* Wk  = (const float*)d_in[6];
    const float* bk  = (const float*)d_in[7];
    const float* Wv  = (const float*)d_in[8];
    const float* bv  = (const float*)d_in[9];
    const float* Wo  = (const float*)d_in[10];
    const float* bo  = (const float*)d_in[11];
    const float* g1  = (const float*)d_in[12];
    const float* be1 = (const float*)d_in[13];
    const float* g2  = (const float*)d_in[14];
    const float* be2 = (const float*)d_in[15];
    const float* W1  = (const float*)d_in[16];
    const float* bf1 = (const float*)d_in[17];
    const float* W2  = (const float*)d_in[18];
    const float* bf2 = (const float*)d_in[19];
    float* ws  = (float*)d_ws;
    float* out = (float*)d_out;

    const int nblk = (N_NODES + 31) / 32;

    // zero den+agg (contiguous 6.8M floats)
    k_zero<<<1024, 256, 0, stream>>>(ws + OFF_DEN, 6800000 / 4);
    dim3 gq(nblk, 3);
    k_node_qkv<<<gq, 256, 0, stream>>>(ns, nt, Wq, bq, Wk, bk, Wv, bv, ws);
    k_edge<<<1024, 256, 0, stream>>>(ei, ee, Wk + 160 * 128, Wv + 160 * 128, ws);
    k_out_ln1<<<nblk, 256, 0, stream>>>(ns, Wo, bo, g1, be1, ws);
    dim3 gf(nblk, 2);
    k_ffn1<<<gf, 256, 0, stream>>>(W1, bf1, ws);
    k_ffn2<<<nblk, 256, 0, stream>>>(W2, bf2, g2, be2, ws, out);
}